// Round 3
// baseline (315.520 us; speedup 1.0000x reference)
//
#include <hip/hip_runtime.h>

#define D_DIM 1024
#define BM 128
#define BN 128
#define BKB 128   // K bytes per LDS stage (fp8 => 128 elements)

typedef unsigned char u8;
typedef __attribute__((ext_vector_type(8))) int int8v;
typedef __attribute__((ext_vector_type(4))) float floatx4;

union frag_u { int4 h[2]; int8v v; };

__device__ __forceinline__ void gl2lds16(const void* g, void* l) {
  __builtin_amdgcn_global_load_lds(
      (const __attribute__((address_space(1))) void*)g,
      (__attribute__((address_space(3))) void*)l, 16, 0, 0);
}

// ---------- prep: fp32 -> fp8 e4m3 + per-row sum of squares (exact fp32) ----------
// wave-per-row: each lane handles 16 consecutive floats -> 16 contiguous fp8 bytes.
__global__ __launch_bounds__(256) void prep_kernel(
    const float* __restrict__ X, const float* __restrict__ S,
    u8* __restrict__ Xb, u8* __restrict__ Sb,
    float* __restrict__ x2, float* __restrict__ s2, int Brows) {
  int wid = blockIdx.x * 4 + (threadIdx.x >> 6);
  int lane = threadIdx.x & 63;
  const float* src; u8* dst; float* sq; int r;
  if (wid < Brows) { src = X; dst = Xb; sq = x2; r = wid; }
  else             { src = S; dst = Sb; sq = s2; r = wid - Brows; }
  const float4* p = (const float4*)(src + (size_t)r * D_DIM);
  float4 v[4];
#pragma unroll
  for (int i = 0; i < 4; i++) v[i] = p[lane * 4 + i];
  float ss = 0.f;
  int4 o;
  int* op = (int*)&o;
#pragma unroll
  for (int i = 0; i < 4; i++) {
    ss += v[i].x * v[i].x + v[i].y * v[i].y + v[i].z * v[i].z + v[i].w * v[i].w;
    int w0 = __builtin_amdgcn_cvt_pk_fp8_f32(v[i].x, v[i].y, 0, false);
    w0 = __builtin_amdgcn_cvt_pk_fp8_f32(v[i].z, v[i].w, w0, true);
    op[i] = w0;
  }
  ((int4*)(dst + (size_t)r * D_DIM))[lane] = o;
#pragma unroll
  for (int m = 32; m > 0; m >>= 1) ss += __shfl_xor(ss, m);
  if (lane == 0) sq[r] = ss;
}

// ---------- fused fp8 GEMM (MX rate, unity scales) + partial logsumexp ----------
// 128x128 tile, BK=128 fp8, 4 waves x (64x64 via 4x4 16x16x128 frags).
// LDS XOR-swizzle: physical 16B chunk p holds logical chunk p ^ (row & 7).
// Unity E8M0 scales (0x7F7F7F7F) => scale-layout-immune; identical k-slot
// packing for A and B => k-permutation-immune.
__global__ __launch_bounds__(256) void gemm_lse_kernel(
    const u8* __restrict__ Xb, const u8* __restrict__ Sb,
    const float* __restrict__ x2, const float* __restrict__ s2,
    const float* __restrict__ g, float2* __restrict__ part, int nCB) {
  __shared__ alignas(16) u8 As[BM * BKB];
  __shared__ alignas(16) u8 Bs[BN * BKB];
  __shared__ float red_m[BM * 2];
  __shared__ float red_l[BM * 2];

  const int tid = threadIdx.x;
  const int w = tid >> 6, lane = tid & 63;
  const int bx = blockIdx.x, by = blockIdx.y;
  const int row0 = by * BM, col0 = bx * BN;
  const int wm = w >> 1, wn = w & 1;
  const int quad = lane >> 4, l15 = lane & 15;
  const int SC1 = 0x7F7F7F7F;   // E8M0 = 127 -> 2^0 in all bytes

  floatx4 acc[4][4];
#pragma unroll
  for (int i = 0; i < 4; i++)
#pragma unroll
    for (int j = 0; j < 4; j++) acc[i][j] = (floatx4){0.f, 0.f, 0.f, 0.f};

  // staging: wave w covers rows w*32..w*32+31 (4 r-steps x 8 rows); lane
  // (lr,p) sources logical chunk p^lr so the tile lands XOR-swizzled.
  const int lr = lane >> 3;
  const int pc = ((lane & 7) ^ lr) * 16;    // source byte offset in row
  const u8* gA = Xb + (size_t)(row0 + w * 32 + lr) * D_DIM + pc;
  const u8* gB = Sb + (size_t)(col0 + w * 32 + lr) * D_DIM + pc;
  u8* lA = As + (w * 32) * BKB;             // wave-uniform base; HW adds lane*16
  u8* lB = Bs + (w * 32) * BKB;

  const int swz = l15 & 7;
  const int c0 = ((quad * 2) ^ swz) * 16;
  const int c1 = ((quad * 2 + 1) ^ swz) * 16;

  for (int k0 = 0; k0 < D_DIM; k0 += BKB) {
#pragma unroll
    for (int r = 0; r < 4; ++r) {
      gl2lds16(gA + (size_t)(r * 8) * D_DIM + k0, lA + r * 8 * BKB);
      gl2lds16(gB + (size_t)(r * 8) * D_DIM + k0, lB + r * 8 * BKB);
    }
    __syncthreads();
    frag_u fb[4];
#pragma unroll
    for (int ni = 0; ni < 4; ni++) {
      int rb = (wn * 64 + ni * 16 + l15) * BKB;
      fb[ni].h[0] = *(const int4*)&Bs[rb + c0];
      fb[ni].h[1] = *(const int4*)&Bs[rb + c1];
    }
#pragma unroll
    for (int mi = 0; mi < 4; mi++) {
      int ra = (wm * 64 + mi * 16 + l15) * BKB;
      frag_u fa;
      fa.h[0] = *(const int4*)&As[ra + c0];
      fa.h[1] = *(const int4*)&As[ra + c1];
#pragma unroll
      for (int ni = 0; ni < 4; ni++)
        acc[mi][ni] = __builtin_amdgcn_mfma_scale_f32_16x16x128_f8f6f4(
            fa.v, fb[ni].v, acc[mi][ni], 0, 0, 0, SC1, 0, SC1);
    }
    __syncthreads();
  }

  // ---- epilogue: dist -> z = s*dist -> per-row (m,l) over 128 cols ----
  const float sgn = -g[0];
  float x2v[4][4];
#pragma unroll
  for (int mi = 0; mi < 4; mi++)
#pragma unroll
    for (int rg = 0; rg < 4; rg++)
      x2v[mi][rg] = x2[row0 + wm * 64 + mi * 16 + quad * 4 + rg];
  float s2v[4];
#pragma unroll
  for (int ni = 0; ni < 4; ni++) s2v[ni] = s2[col0 + wn * 64 + ni * 16 + l15];

#pragma unroll
  for (int mi = 0; mi < 4; mi++) {
#pragma unroll
    for (int rg = 0; rg < 4; rg++) {
      float zv[4];
      float mr = -3.4e38f;
#pragma unroll
      for (int ni = 0; ni < 4; ni++) {
        float dist = x2v[mi][rg] + s2v[ni] - 2.f * acc[mi][ni][rg];
        dist = fmaxf(dist, 0.f);
        float z = sgn * dist;
        zv[ni] = z;
        mr = fmaxf(mr, z);
      }
      float lr2 = 0.f;
#pragma unroll
      for (int ni = 0; ni < 4; ni++) lr2 += __expf(zv[ni] - mr);
#pragma unroll
      for (int mask = 1; mask < 16; mask <<= 1) {
        float mo = __shfl_xor(mr, mask);
        float lo = __shfl_xor(lr2, mask);
        float mn = fmaxf(mr, mo);
        lr2 = lr2 * __expf(mr - mn) + lo * __expf(mo - mn);
        mr = mn;
      }
      if (l15 == 0) {
        int rl = wm * 64 + mi * 16 + quad * 4 + rg;
        red_m[rl * 2 + wn] = mr;
        red_l[rl * 2 + wn] = lr2;
      }
    }
  }
  __syncthreads();
  if (tid < BM) {
    float ma = red_m[tid * 2 + 0], la = red_l[tid * 2 + 0];
    float mb = red_m[tid * 2 + 1], lb = red_l[tid * 2 + 1];
    float mn = fmaxf(ma, mb);
    float l = la * __expf(ma - mn) + lb * __expf(mb - mn);
    part[(size_t)(row0 + tid) * nCB + bx] = make_float2(mn, l);
  }
}

// ---------- finalize: merge 128 partials per row -> output ----------
__global__ __launch_bounds__(256) void finalize_kernel(
    const float2* __restrict__ part, const float* __restrict__ g,
    float* __restrict__ out, int nCB, int Ntot) {
  int w = threadIdx.x >> 6, lane = threadIdx.x & 63;
  int row = blockIdx.x * 4 + w;
  const float2* p = part + (size_t)row * nCB;
  float2 a = p[lane];
  float2 b = p[lane + 64];
  float m = fmaxf(a.x, b.x);
  float l = a.y * __expf(a.x - m) + b.y * __expf(b.x - m);
#pragma unroll
  for (int mask = 1; mask < 64; mask <<= 1) {
    float mo = __shfl_xor(m, mask);
    float lo = __shfl_xor(l, mask);
    float mn = fmaxf(m, mo);
    l = l * __expf(m - mn) + lo * __expf(mo - mn);
    m = mn;
  }
  if (lane == 0) {
    float sgn = -g[0];
    out[row] = (m + logf(l) - logf((float)Ntot)) / sgn;
  }
}

extern "C" void kernel_launch(void* const* d_in, const int* in_sizes, int n_in,
                              void* d_out, int out_size, void* d_ws, size_t ws_size,
                              hipStream_t stream) {
  const float* X = (const float*)d_in[0];
  const float* S = (const float*)d_in[1];
  const float* g = (const float*)d_in[2];
  float* out = (float*)d_out;
  const int Bt = in_sizes[0] / D_DIM;   // 4096
  const int Nt = in_sizes[1] / D_DIM;   // 16384
  const int nCB = Nt / BN;              // 128

  char* ws = (char*)d_ws;
  size_t off = 0;
  float2* part = (float2*)(ws + off); off += (size_t)Bt * nCB * sizeof(float2); // 4 MB
  float* x2 = (float*)(ws + off);     off += (size_t)Bt * sizeof(float);
  float* s2 = (float*)(ws + off);     off += (size_t)Nt * sizeof(float);
  off = (off + 255) & ~(size_t)255;
  u8* Xb = (u8*)(ws + off); off += (size_t)Bt * D_DIM;   // 4 MB
  u8* Sb = (u8*)(ws + off); off += (size_t)Nt * D_DIM;   // 16 MB

  prep_kernel<<<(Bt + Nt) / 4, 256, 0, stream>>>(X, S, Xb, Sb, x2, s2, Bt);
  dim3 grid(nCB, Bt / BM);
  gemm_lse_kernel<<<grid, 256, 0, stream>>>(Xb, Sb, x2, s2, g, part, nCB);
  finalize_kernel<<<Bt / 4, 256, 0, stream>>>(part, g, out, nCB, Nt);
}